// Round 8
// baseline (371.064 us; speedup 1.0000x reference)
//
#include <hip/hip_runtime.h>
#include <hip/hip_bf16.h>

#define NN   100000
#define NE   1600000
#define FIN  256
#define HID  32
#define OUTD 16

#define NB    391                 // coarse buckets = ceil(NN/256), bucket = dst>>8
#define NHB   256                 // hist/scatter edge-partition blocks
#define EPB   (NE / NHB)          // 6250 edges per partition (exact)
#define GEMM_BLOCKS ((NN + 127) / 128)   // 782

// ---- workspace layout (32-bit word offsets), total 9,900,992 words = 39.6 MB ----
#define OFF_FLAG    0                        // [0]=is64, [1]=isf32
#define OFF_HIST    64                       // NHB*NB = 100,096 ints
#define OFF_TOT     (OFF_HIST + NHB*NB)      // 392 ints
#define OFF_BASE    (OFF_TOT + 392)          // 392 ints (base[0..NB], base[NB]=NE)
#define OFF_ROWPTR  (OFF_BASE + 392)         // NN+1 ints (off=100,944, even)
#define OFF_DINV    (OFF_ROWPTR + NN + 32)   // NN floats (200,976)
#define OFF_TEMP    (OFF_DINV + NN + 16)     // 2*NE words int2 (300,992, even)
#define OFF_CSR     (OFF_TEMP + 2*NE)        // 2*NE words int2 (3,500,992)
#define OFF_H1      (OFF_CSR + 2*NE)         // NN*HID floats (6,700,992)
#define OFF_P2S     OFF_TEMP                 // alias: TEMP dead before gather1 writes p2s

__device__ __forceinline__ float bf2f(unsigned short u) {
  union { unsigned int i; float f; } v; v.i = ((unsigned int)u) << 16; return v.f;
}
__device__ __forceinline__ unsigned short f2bf(float f) {
  union { float f; unsigned int i; } v; v.f = f;
  unsigned int x = v.i;
  return (unsigned short)((x + 0x7fffu + ((x >> 16) & 1u)) >> 16); // RNE
}
__device__ __forceinline__ int eidx(const int* __restrict__ ei, long long pos, int is64) {
  return is64 ? ei[2 * pos] : ei[pos];
}
__device__ __forceinline__ float ldf(const void* p, long long i, int isf32) {
  return isf32 ? ((const float*)p)[i] : bf2f(((const unsigned short*)p)[i]);
}

// ---- K0: detect (a) int64 vs int32 edge_index, (b) f32 vs bf16 floats ----
__global__ __launch_bounds__(256) void detect_kernel(const int* __restrict__ ei,
    const unsigned short* __restrict__ xu, int* __restrict__ flags) {
  __shared__ int any, cnt;
  if (threadIdx.x == 0) { any = 0; cnt = 0; }
  __syncthreads();
  int local = 0, c = 0;
  for (int i = threadIdx.x; i < 2048; i += 256) local |= ei[2 * i + 1];
  for (int i = threadIdx.x; i < 1024; i += 256) {
    unsigned int e = (xu[2 * i] >> 7) & 0xFF;
    c += (e < 100 || e > 140) ? 1 : 0;
  }
  if (local) atomicOr(&any, 1);
  atomicAdd(&cnt, c);
  __syncthreads();
  if (threadIdx.x == 0) {
    flags[0] = (any == 0) ? 1 : 0;   // 1 => int64 layout
    flags[1] = (cnt > 100) ? 1 : 0;  // 1 => f32 floats
  }
}

// ---- K1: per-partition coarse histogram (LDS atomics only) ----
__global__ __launch_bounds__(256) void hist_kernel(const int* __restrict__ ei,
    int* __restrict__ hist, const int* __restrict__ flags) {
  __shared__ int lh[NB];
  int b = blockIdx.x, t = threadIdx.x;
  for (int i = t; i < NB; i += 256) lh[i] = 0;
  __syncthreads();
  int is64 = flags[0];
  long long e0 = (long long)b * EPB;
  for (int i = t; i < EPB; i += 256) {
    int dst = eidx(ei, (long long)NE + e0 + i, is64);
    atomicAdd(&lh[dst >> 8], 1);
  }
  __syncthreads();
  for (int i = t; i < NB; i += 256) hist[b * NB + i] = lh[i];
}

// ---- K2: per-bucket exclusive scan over the 256 partitions (in-place) ----
__global__ __launch_bounds__(256) void scan_cols_kernel(int* __restrict__ hist,
                                                        int* __restrict__ tot) {
  __shared__ int a[256];
  int b = blockIdx.x, t = threadIdx.x;
  int orig = hist[t * NB + b];
  a[t] = orig;
  __syncthreads();
  for (int off = 1; off < 256; off <<= 1) {
    int v = a[t] + ((t >= off) ? a[t - off] : 0);
    __syncthreads(); a[t] = v; __syncthreads();
  }
  hist[t * NB + b] = a[t] - orig;        // exclusive within bucket
  if (t == 255) tot[b] = a[255];
}

// ---- K3: exclusive scan of bucket totals -> bucket bases ----
__global__ __launch_bounds__(512) void scan_base_kernel(const int* __restrict__ tot,
    int* __restrict__ base, int* __restrict__ rowptr) {
  __shared__ int a[512];
  int t = threadIdx.x;
  int orig = (t < NB) ? tot[t] : 0;
  a[t] = orig;
  __syncthreads();
  for (int off = 1; off < 512; off <<= 1) {
    int v = a[t] + ((t >= off) ? a[t - off] : 0);
    __syncthreads(); a[t] = v; __syncthreads();
  }
  if (t < NB) base[t] = a[t] - orig;
  if (t == 0) { base[NB] = NE; rowptr[NN] = NE; }
}

// ---- K4 FUSED: coarse scatter (atomic-free positions) + gemm1, 3:1 interleave ----
__global__ __launch_bounds__(256) void scatter_gemm_kernel(const int* __restrict__ ei,
    const void* __restrict__ ew, const int* __restrict__ hist,
    const int* __restrict__ base, int2* __restrict__ temp,
    const void* __restrict__ x, const void* __restrict__ W1,
    float* __restrict__ h1, const int* __restrict__ flags) {
  __shared__ float wlds[FIN][HID];   // 32 KB (gemm); SC overlays ints on it
  __shared__ float xs[32][132];      // 16.5 KB (gemm)
  int b = blockIdx.x, t = threadIdx.x;
  int r4 = b & 3;

  if (r4 == 3) {
    // ---- scatter body ----
    int scid = b >> 2;
    if (scid >= NHB) return;
    int* lbase = (int*)wlds;          // NB ints
    int* lcnt  = ((int*)wlds) + 512;  // NB ints
    for (int i = t; i < NB; i += 256) {
      lbase[i] = base[i] + hist[scid * NB + i];
      lcnt[i] = 0;
    }
    __syncthreads();
    int is64 = flags[0], isf32 = flags[1];
    long long e0 = (long long)scid * EPB;
    for (int i = t; i < EPB; i += 256) {
      long long e = e0 + i;
      int src = eidx(ei, e, is64);
      int dst = eidx(ei, (long long)NE + e, is64);
      float w = ldf(ew, e, isf32);
      int bk = dst >> 8;
      int r = atomicAdd(&lcnt[bk], 1);        // LDS atomic (fast)
      int2 rec; rec.x = src | ((dst & 255) << 17); rec.y = __float_as_int(w);
      temp[lbase[bk] + r] = rec;
    }
    return;
  }

  // ---- gemm1 body: h1 = x @ W1 (raw, scaled by dinv later in build) ----
  int gid = (b >> 2) * 3 + r4;
  if (gid >= GEMM_BLOCKS) return;
  int rb = gid * 128;
  int isf32 = flags[1];

  if (isf32) {
    const float* wrow = (const float*)W1 + t * HID;
    #pragma unroll
    for (int jj = 0; jj < HID; jj += 4)
      *(float4*)&wlds[t][jj] = *((const float4*)(wrow + jj));
  } else {
    const unsigned short* wrow = (const unsigned short*)W1 + t * HID;
    #pragma unroll
    for (int jj = 0; jj < HID; jj += 8) {
      uint4 pk = *((const uint4*)(wrow + jj));
      const unsigned short* pu = (const unsigned short*)&pk;
      #pragma unroll
      for (int q = 0; q < 8; q++) wlds[t][jj + q] = bf2f(pu[q]);
    }
  }

  int j0 = (t & 15) * 2;
  int r0 = (t >> 4) * 8;
  float acc[8][2];
  #pragma unroll
  for (int i = 0; i < 8; i++) { acc[i][0] = 0.f; acc[i][1] = 0.f; }

  for (int kc = 0; kc < FIN; kc += 32) {
    __syncthreads();
    {
      int rr = t >> 1;
      int kk0 = (t & 1) * 16;
      int grow = rb + rr;
      if (grow < NN) {
        if (isf32) {
          const float* xp = (const float*)x + (long long)grow * FIN + kc + kk0;
          #pragma unroll
          for (int q4 = 0; q4 < 4; q4++) {
            float4 p = ((const float4*)xp)[q4];
            xs[kk0 + q4 * 4 + 0][rr] = p.x;
            xs[kk0 + q4 * 4 + 1][rr] = p.y;
            xs[kk0 + q4 * 4 + 2][rr] = p.z;
            xs[kk0 + q4 * 4 + 3][rr] = p.w;
          }
        } else {
          const unsigned short* xp = (const unsigned short*)x + (long long)grow * FIN + kc + kk0;
          uint4 p0 = ((const uint4*)xp)[0];
          uint4 p1 = ((const uint4*)xp)[1];
          const unsigned short* pu = (const unsigned short*)&p0;
          #pragma unroll
          for (int q = 0; q < 8; q++) xs[kk0 + q][rr] = bf2f(pu[q]);
          pu = (const unsigned short*)&p1;
          #pragma unroll
          for (int q = 0; q < 8; q++) xs[kk0 + 8 + q][rr] = bf2f(pu[q]);
        }
      } else {
        #pragma unroll
        for (int q = 0; q < 16; q++) xs[kk0 + q][rr] = 0.f;
      }
    }
    __syncthreads();
    #pragma unroll 8
    for (int kk = 0; kk < 32; kk++) {
      float w0 = wlds[kc + kk][j0];
      float w1 = wlds[kc + kk][j0 + 1];
      const float4* xr = (const float4*)&xs[kk][r0];
      float4 xa = xr[0], xb = xr[1];
      float xv[8] = {xa.x, xa.y, xa.z, xa.w, xb.x, xb.y, xb.z, xb.w};
      #pragma unroll
      for (int i = 0; i < 8; i++) {
        acc[i][0] = fmaf(xv[i], w0, acc[i][0]);
        acc[i][1] = fmaf(xv[i], w1, acc[i][1]);
      }
    }
  }
  #pragma unroll
  for (int i = 0; i < 8; i++) {
    int grow = rb + r0 + i;
    if (grow < NN) {
      float2 v; v.x = acc[i][0]; v.y = acc[i][1];
      *((float2*)(h1 + (long long)grow * HID + j0)) = v;
    }
  }
}

// ---- K5: per-bucket build: rowptr + dinv + sorted CSR + h1 *= dinv (in-place) ----
__global__ __launch_bounds__(256) void build_kernel(const int2* __restrict__ temp,
    const int* __restrict__ base, int* __restrict__ rowptr,
    float* __restrict__ dinv, int2* __restrict__ csr, float* __restrict__ h1) {
  __shared__ int   cnt[256];
  __shared__ float wsum[256];
  __shared__ int   roff[256];
  __shared__ float dnv[256];
  __shared__ int   sbuf[256];
  int b = blockIdx.x, t = threadIdx.x;
  cnt[t] = 0; wsum[t] = 0.f;
  __syncthreads();
  int e0 = base[b], e1 = base[b + 1];
  for (int e = e0 + t; e < e1; e += 256) {
    int2 rec = temp[e];
    int dl = (rec.x >> 17) & 255;
    atomicAdd(&cnt[dl], 1);
    atomicAdd(&wsum[dl], __int_as_float(rec.y));
  }
  __syncthreads();
  int orig = cnt[t];
  sbuf[t] = orig;
  __syncthreads();
  for (int off = 1; off < 256; off <<= 1) {
    int v = sbuf[t] + ((t >= off) ? sbuf[t - off] : 0);
    __syncthreads(); sbuf[t] = v; __syncthreads();
  }
  roff[t] = sbuf[t] - orig;   // exclusive local offsets
  int nb0 = b * 256;
  int node = nb0 + t;
  if (node < NN) {
    rowptr[node] = e0 + roff[t];
    float dv = rsqrtf(wsum[t] + 1.0f);   // + self-loop weight 1
    dinv[node] = dv;
    dnv[t] = dv;
  }
  cnt[t] = 0;                 // reuse as rank counters
  __syncthreads();
  // scale h1 rows of this bucket in place (coalesced)
  int nn = NN - nb0; if (nn > 256) nn = 256;
  for (int idx = t; idx < nn * HID; idx += 256) {
    int nl = idx >> 5, j = idx & 31;
    h1[(nb0 + nl) * HID + j] *= dnv[nl];
  }
  // permute records into node-sorted CSR (plain w kept)
  for (int e = e0 + t; e < e1; e += 256) {
    int2 rec = temp[e];
    int dl = (rec.x >> 17) & 255;
    int r = atomicAdd(&cnt[dl], 1);
    int2 o; o.x = rec.x & 0x1FFFF; o.y = rec.y;
    csr[e0 + roff[dl] + r] = o;
  }
}

// ---- K6: gather1: acc=Σ w·h1s[src] + h1s[c]; pre=b1+dinv[c]·acc; ReLU; @W2; p2s=dinv[c]·proj ----
__global__ __launch_bounds__(256) void gather1_kernel(const float* __restrict__ h1,
    const float* __restrict__ dinv, const int* __restrict__ rowptr,
    const int2* __restrict__ csr, const void* __restrict__ b1,
    const void* __restrict__ W2, float* __restrict__ p2s,
    const int* __restrict__ flags) {
  __shared__ float w2lds[HID * OUTD];
  __shared__ float b1l[HID];
  __shared__ float tl[8][HID + 1];
  __shared__ float dloc[8];
  int t = threadIdx.x;
  int isf32 = flags[1];
  w2lds[2 * t]     = ldf(W2, 2 * t, isf32);
  w2lds[2 * t + 1] = ldf(W2, 2 * t + 1, isf32);
  if (t < HID) b1l[t] = ldf(b1, t, isf32);
  __syncthreads();

  int nl = t >> 5;
  int j  = t & 31;
  int node = blockIdx.x * 8 + nl;
  if (node < NN) {
    int k0 = rowptr[node], k1 = rowptr[node + 1];
    float acc = 0.f;
    int k = k0;
    for (; k + 8 <= k1; k += 8) {
      int2 q0 = csr[k];     int2 q1 = csr[k + 1];
      int2 q2 = csr[k + 2]; int2 q3 = csr[k + 3];
      int2 q4 = csr[k + 4]; int2 q5 = csr[k + 5];
      int2 q6 = csr[k + 6]; int2 q7 = csr[k + 7];
      float v0 = h1[q0.x * HID + j]; float v1 = h1[q1.x * HID + j];
      float v2 = h1[q2.x * HID + j]; float v3 = h1[q3.x * HID + j];
      float v4 = h1[q4.x * HID + j]; float v5 = h1[q5.x * HID + j];
      float v6 = h1[q6.x * HID + j]; float v7 = h1[q7.x * HID + j];
      acc = fmaf(__int_as_float(q0.y), v0, acc);
      acc = fmaf(__int_as_float(q1.y), v1, acc);
      acc = fmaf(__int_as_float(q2.y), v2, acc);
      acc = fmaf(__int_as_float(q3.y), v3, acc);
      acc = fmaf(__int_as_float(q4.y), v4, acc);
      acc = fmaf(__int_as_float(q5.y), v5, acc);
      acc = fmaf(__int_as_float(q6.y), v6, acc);
      acc = fmaf(__int_as_float(q7.y), v7, acc);
    }
    for (; k + 4 <= k1; k += 4) {
      int2 q0 = csr[k];     int2 q1 = csr[k + 1];
      int2 q2 = csr[k + 2]; int2 q3 = csr[k + 3];
      float v0 = h1[q0.x * HID + j]; float v1 = h1[q1.x * HID + j];
      float v2 = h1[q2.x * HID + j]; float v3 = h1[q3.x * HID + j];
      acc = fmaf(__int_as_float(q0.y), v0, acc);
      acc = fmaf(__int_as_float(q1.y), v1, acc);
      acc = fmaf(__int_as_float(q2.y), v2, acc);
      acc = fmaf(__int_as_float(q3.y), v3, acc);
    }
    for (; k < k1; k++) {
      int2 pr = csr[k];
      acc = fmaf(__int_as_float(pr.y), h1[pr.x * HID + j], acc);
    }
    acc += h1[node * HID + j];              // self-loop: h1s[c]
    float di = dinv[node];
    if (j == 0) dloc[nl] = di;
    tl[nl][j] = fmaxf(fmaf(di, acc, b1l[j]), 0.f);
  }
  __syncthreads();
  int m = t & 31;
  if (node < NN && m < OUTD) {
    float s = 0.f;
    #pragma unroll
    for (int k = 0; k < HID; k++) s = fmaf(tl[nl][k], w2lds[k * OUTD + m], s);
    p2s[node * OUTD + m] = dloc[nl] * s;    // p2s = dinv * proj
  }
}

// ---- K7: gather2: acc=Σ w·p2s[src] + p2s[c]; out=b2+dinv[c]·acc ----
__global__ __launch_bounds__(256) void gather2_kernel(const float* __restrict__ p2s,
    const float* __restrict__ dinv, const int* __restrict__ rowptr,
    const int2* __restrict__ csr, const void* __restrict__ b2,
    void* __restrict__ out, const int* __restrict__ flags) {
  __shared__ float b2l[OUTD];
  int t = threadIdx.x;
  int isf32 = flags[1];
  if (t < OUTD) b2l[t] = ldf(b2, t, isf32);
  __syncthreads();

  int nl = t >> 4;
  int m  = t & 15;
  int node = blockIdx.x * 16 + nl;
  if (node >= NN) return;
  int k0 = rowptr[node], k1 = rowptr[node + 1];
  float acc = 0.f;
  int k = k0;
  for (; k + 8 <= k1; k += 8) {
    int2 q0 = csr[k];     int2 q1 = csr[k + 1];
    int2 q2 = csr[k + 2]; int2 q3 = csr[k + 3];
    int2 q4 = csr[k + 4]; int2 q5 = csr[k + 5];
    int2 q6 = csr[k + 6]; int2 q7 = csr[k + 7];
    float v0 = p2s[q0.x * OUTD + m]; float v1 = p2s[q1.x * OUTD + m];
    float v2 = p2s[q2.x * OUTD + m]; float v3 = p2s[q3.x * OUTD + m];
    float v4 = p2s[q4.x * OUTD + m]; float v5 = p2s[q5.x * OUTD + m];
    float v6 = p2s[q6.x * OUTD + m]; float v7 = p2s[q7.x * OUTD + m];
    acc = fmaf(__int_as_float(q0.y), v0, acc);
    acc = fmaf(__int_as_float(q1.y), v1, acc);
    acc = fmaf(__int_as_float(q2.y), v2, acc);
    acc = fmaf(__int_as_float(q3.y), v3, acc);
    acc = fmaf(__int_as_float(q4.y), v4, acc);
    acc = fmaf(__int_as_float(q5.y), v5, acc);
    acc = fmaf(__int_as_float(q6.y), v6, acc);
    acc = fmaf(__int_as_float(q7.y), v7, acc);
  }
  for (; k + 4 <= k1; k += 4) {
    int2 q0 = csr[k];     int2 q1 = csr[k + 1];
    int2 q2 = csr[k + 2]; int2 q3 = csr[k + 3];
    float v0 = p2s[q0.x * OUTD + m]; float v1 = p2s[q1.x * OUTD + m];
    float v2 = p2s[q2.x * OUTD + m]; float v3 = p2s[q3.x * OUTD + m];
    acc = fmaf(__int_as_float(q0.y), v0, acc);
    acc = fmaf(__int_as_float(q1.y), v1, acc);
    acc = fmaf(__int_as_float(q2.y), v2, acc);
    acc = fmaf(__int_as_float(q3.y), v3, acc);
  }
  for (; k < k1; k++) {
    int2 pr = csr[k];
    acc = fmaf(__int_as_float(pr.y), p2s[pr.x * OUTD + m], acc);
  }
  acc += p2s[node * OUTD + m];              // self-loop: p2s[c]
  float v = fmaf(dinv[node], acc, b2l[m]);
  int oidx = node * OUTD + m;
  if (isf32) ((float*)out)[oidx] = v;
  else       ((unsigned short*)out)[oidx] = f2bf(v);
}

extern "C" void kernel_launch(void* const* d_in, const int* in_sizes, int n_in,
                              void* d_out, int out_size, void* d_ws, size_t ws_size,
                              hipStream_t stream) {
  const void* x  = d_in[0];
  const int* ei  = (const int*)d_in[1];
  const void* ew = d_in[2];
  const void* W1 = d_in[3];
  const void* b1 = d_in[4];
  const void* W2 = d_in[5];
  const void* b2 = d_in[6];
  float* ws = (float*)d_ws;
  int* wsi = (int*)d_ws;

  detect_kernel<<<dim3(1), dim3(256), 0, stream>>>(ei, (const unsigned short*)x, wsi + OFF_FLAG);
  hist_kernel<<<dim3(NHB), dim3(256), 0, stream>>>(ei, wsi + OFF_HIST, wsi + OFF_FLAG);
  scan_cols_kernel<<<dim3(NB), dim3(256), 0, stream>>>(wsi + OFF_HIST, wsi + OFF_TOT);
  scan_base_kernel<<<dim3(1), dim3(512), 0, stream>>>(wsi + OFF_TOT, wsi + OFF_BASE, wsi + OFF_ROWPTR);
  scatter_gemm_kernel<<<dim3(1042), dim3(256), 0, stream>>>(ei, ew, wsi + OFF_HIST,
      wsi + OFF_BASE, (int2*)(wsi + OFF_TEMP), x, W1, ws + OFF_H1, wsi + OFF_FLAG);
  build_kernel<<<dim3(NB), dim3(256), 0, stream>>>((const int2*)(wsi + OFF_TEMP),
      wsi + OFF_BASE, wsi + OFF_ROWPTR, ws + OFF_DINV, (int2*)(wsi + OFF_CSR), ws + OFF_H1);
  gather1_kernel<<<dim3((NN + 7) / 8), dim3(256), 0, stream>>>(ws + OFF_H1, ws + OFF_DINV,
      wsi + OFF_ROWPTR, (const int2*)(wsi + OFF_CSR), b1, W2, ws + OFF_P2S, wsi + OFF_FLAG);
  gather2_kernel<<<dim3((NN + 15) / 16), dim3(256), 0, stream>>>(ws + OFF_P2S, ws + OFF_DINV,
      wsi + OFF_ROWPTR, (const int2*)(wsi + OFF_CSR), b2, d_out, wsi + OFF_FLAG);
}